// Round 1
// baseline (166.992 us; speedup 1.0000x reference)
//
#include <hip/hip_runtime.h>

// Batched 10-qubit statevector simulator.
// One 64-lane wave per batch sample. State = 1024 complex amplitudes:
//   state index s (10 bits), qubit q <-> bit (9-q).
//   r = s >> 6  (4 bits, qubits 0..3)  -> per-lane register index (16 complex)
//   lane = s & 63 (6 bits, qubits 4..9) -> lane index; qubit q <-> lane bit (9-q)
// Per layer, the 4 single-qubit gates on each qubit (RY(a) RZ(b) RZ(g) RY(d),
// reordered via commutation across distinct qubits) fuse into one SU(2)
// unitary U = [[u, -conj(v)], [v, conj(u)]]:
//   u = (cd*ca - sd*sa)*cp - i*(cd*ca + sd*sa)*sp
//   v = (cd*sa + sd*ca)*cp + i*(cd*sa - sd*ca)*sp,  p = (b+g)/2

constexpr int NQ   = 10;
constexpr int NL   = 5;
constexpr int OBS  = 10;

__global__ __launch_bounds__(256) void qsim_kernel(
    const float* __restrict__ x,       // (B, 10)
    const float* __restrict__ isc,     // (5, 20)
    const float* __restrict__ w,       // (5, 20)
    const float* __restrict__ oscale,  // (4)
    float* __restrict__ out,           // (B, 4)
    int B)
{
    const int lane = threadIdx.x & 63;
    const int wid  = (blockIdx.x * blockDim.x + threadIdx.x) >> 6;
    if (wid >= B) return;

    float ar[16], ai[16];
#pragma unroll
    for (int r = 0; r < 16; ++r) { ar[r] = 0.f; ai[r] = 0.f; }
    ar[0] = (lane == 0) ? 1.f : 0.f;   // |0...0>

    float xv[OBS];
#pragma unroll
    for (int i = 0; i < OBS; ++i) xv[i] = x[wid * OBS + i];

#define SWAPR(i, j) { float _tr = ar[i], _ti = ai[i]; \
                      ar[i] = ar[j]; ai[i] = ai[j];   \
                      ar[j] = _tr;  ai[j] = _ti; }

    for (int layer = 0; layer < NL; ++layer) {
        const float* iscL = isc + layer * 2 * NQ;
        const float* wL   = w   + layer * 2 * NQ;

        // ---- fused single-qubit unitaries, one per qubit ----
#pragma unroll
        for (int q = 0; q < NQ; ++q) {
            const float alpha = iscL[q]      * xv[q];
            const float beta  = iscL[q + NQ] * xv[q];
            const float gamma = wL[q];
            const float delta = wL[q + NQ];
            float sa, ca, sp, cp, sd, cd;
            __sincosf(0.5f * alpha,          &sa, &ca);
            __sincosf(0.5f * (beta + gamma), &sp, &cp);
            __sincosf(0.5f * delta,          &sd, &cd);
            const float A  = cd * ca, Bt = sd * sa;
            const float C  = cd * sa, D  = sd * ca;
            const float ur = (A - Bt) * cp;
            const float ui = -(A + Bt) * sp;
            const float vr = (C + D) * cp;
            const float vi = (C - D) * sp;

            if (q < 4) {
                // register-bit qubit: pair stride m inside the lane
                const int m = 1 << (3 - q);
#pragma unroll
                for (int r0 = 0; r0 < 16; ++r0) {
                    if (r0 & m) continue;
                    const int r1 = r0 | m;
                    const float s0r = ar[r0], s0i = ai[r0];
                    const float s1r = ar[r1], s1i = ai[r1];
                    // new0 = u*s0 - conj(v)*s1 ; new1 = v*s0 + conj(u)*s1
                    ar[r0] = ur*s0r - ui*s0i - vr*s1r - vi*s1i;
                    ai[r0] = ur*s0i + ui*s0r - vr*s1i + vi*s1r;
                    ar[r1] = vr*s0r - vi*s0i + ur*s1r + ui*s1i;
                    ai[r1] = vr*s0i + vi*s0r + ur*s1i - ui*s1r;
                }
            } else {
                // lane-bit qubit: butterfly exchange with lane^M
                const int  M   = 1 << (9 - q);
                const bool bit = (lane & M) != 0;
                // mine-coeff P, partner-coeff Q:
                //  bit0: new = u*mine - conj(v)*partner
                //  bit1: new = conj(u)*mine + v*partner
                const float Pi = bit ? -ui : ui;     // Pr = ur always
                const float Qr = bit ?  vr : -vr;    // Qi = vi always
#pragma unroll
                for (int r = 0; r < 16; ++r) {
                    const float pr = __shfl_xor(ar[r], M, 64);
                    const float pi = __shfl_xor(ai[r], M, 64);
                    const float mr = ar[r], mi = ai[r];
                    ar[r] = ur*mr - Pi*mi + Qr*pr - vi*pi;
                    ai[r] = ur*mi + Pi*mr + Qr*pi + vi*pr;
                }
            }
        }

        // ---- CNOT ring: (0,1),(1,2),...,(8,9),(9,0), sequential ----
        // CNOT(0,1): ctrl r-bit3, tgt r-bit2 -> register swap
        SWAPR(8, 12) SWAPR(9, 13) SWAPR(10, 14) SWAPR(11, 15)
        // CNOT(1,2): ctrl r-bit2, tgt r-bit1
        SWAPR(4, 6)  SWAPR(5, 7)  SWAPR(12, 14) SWAPR(13, 15)
        // CNOT(2,3): ctrl r-bit1, tgt r-bit0
        SWAPR(2, 3)  SWAPR(6, 7)  SWAPR(10, 11) SWAPR(14, 15)
        // CNOT(3,4): ctrl r-bit0 (r odd), tgt lane-bit5 (mask 32)
#pragma unroll
        for (int r = 1; r < 16; r += 2) {
            const float tr = __shfl_xor(ar[r], 32, 64);
            const float ti = __shfl_xor(ai[r], 32, 64);
            ar[r] = tr; ai[r] = ti;
        }
        // CNOT(q,q+1) for q=4..8: ctrl lane mask Mc, tgt mask Mc>>1
#pragma unroll
        for (int q = 4; q <= 8; ++q) {
            const int  Mc  = 1 << (9 - q);
            const int  Mt  = Mc >> 1;
            const bool ctl = (lane & Mc) != 0;
#pragma unroll
            for (int r = 0; r < 16; ++r) {
                const float tr = __shfl_xor(ar[r], Mt, 64);
                const float ti = __shfl_xor(ai[r], Mt, 64);
                if (ctl) { ar[r] = tr; ai[r] = ti; }
            }
        }
        // CNOT(9,0): ctrl lane-bit0, tgt r-bit3 -> conditional register swap
        {
            const bool ctl = (lane & 1) != 0;
#pragma unroll
            for (int r = 0; r < 8; ++r) {
                const float t0r = ar[r],     t0i = ai[r];
                const float t1r = ar[r + 8], t1i = ai[r + 8];
                ar[r]     = ctl ? t1r : t0r;
                ai[r]     = ctl ? t1i : t0i;
                ar[r + 8] = ctl ? t0r : t1r;
                ai[r + 8] = ctl ? t0i : t1i;
            }
        }
    }

    // ---- <Z_i> for qubits 0..3 (all register bits) ----
    float z0 = 0.f, z1 = 0.f, z2 = 0.f, z3 = 0.f;
#pragma unroll
    for (int r = 0; r < 16; ++r) {
        const float pv = ar[r] * ar[r] + ai[r] * ai[r];
        z0 += (r & 8) ? -pv : pv;
        z1 += (r & 4) ? -pv : pv;
        z2 += (r & 2) ? -pv : pv;
        z3 += (r & 1) ? -pv : pv;
    }
#pragma unroll
    for (int m = 1; m < 64; m <<= 1) {
        z0 += __shfl_xor(z0, m, 64);
        z1 += __shfl_xor(z1, m, 64);
        z2 += __shfl_xor(z2, m, 64);
        z3 += __shfl_xor(z3, m, 64);
    }
    if (lane == 0) {
        out[wid * 4 + 0] = z0 * oscale[0];
        out[wid * 4 + 1] = z1 * oscale[1];
        out[wid * 4 + 2] = z2 * oscale[2];
        out[wid * 4 + 3] = z3 * oscale[3];
    }
#undef SWAPR
}

extern "C" void kernel_launch(void* const* d_in, const int* in_sizes, int n_in,
                              void* d_out, int out_size, void* d_ws, size_t ws_size,
                              hipStream_t stream) {
    const float* x      = (const float*)d_in[0];
    const float* isc    = (const float*)d_in[1];
    const float* w      = (const float*)d_in[2];
    const float* oscale = (const float*)d_in[3];
    float* out = (float*)d_out;

    const int B = in_sizes[0] / OBS;             // 4096
    const int threads = 256;                     // 4 waves -> 4 samples per block
    const int blocks = (B * 64 + threads - 1) / threads;
    qsim_kernel<<<blocks, threads, 0, stream>>>(x, isc, w, oscale, out, B);
}